// Round 15
// baseline (104.353 us; speedup 1.0000x reference)
//
#include <hip/hip_runtime.h>
#include <hip/hip_bf16.h>

// Binarized-weight conv2d: x[32][256][56][56] (f32), W[256][256][3][3] (sign)
// -> out[32][256][56][56] (f32), stride 1, pad 1.
// R15: i8 implicit GEMM, m201-faithful micro-phase schedule on R11 regions.
//   Per K-tile (buf t%3 of 3): 4 phases {2 X ds_reads (+4 W in P1) | 1 stage
//   GLD for tile t+2 | barrier | lgkmcnt(0) | setprio 8 MFMA | [vmcnt(4) P4]
//   | closing barrier}. 2-tile stage lead, 1 GLD/phase, 96KB LDS.

#define N_IMG   32
#define C_IN    256
#define C_OUT   256
#define HW      56
#define HP      58
#define PIX     (HW*HW)      // 3136
#define M_TOT   (N_IMG*PIX)  // 100352
#define K_TOT   (C_IN*9)     // 2304

#define WQ_BYTES   (C_OUT * K_TOT)                 // 589824
#define XPAD_BYTES (N_IMG * HP * HP * C_IN)        // 27,557,888
#define WS_NEEDED  (WQ_BYTES + XPAD_BYTES)

#define BM      224
#define NBLK    (M_TOT / BM)   // 448 = 8*56
#define NT      36             // K tiles of 64

#define QCLIP   5.5f

typedef int   i32x4 __attribute__((ext_vector_type(4)));

// ---------------- W binarize + reorder: OIHW f32 -> [co][khkw*256+ci] i8 (+-1)
__global__ void __launch_bounds__(256) binW_kernel(const float* __restrict__ W,
                                                   unsigned int* __restrict__ wq4) {
    int i4 = blockIdx.x * 256 + threadIdx.x;         // over 147456
    int base = i4 * 4;
    int co = base / K_TOT;
    int k  = base - co * K_TOT;
    int khkw = k >> 8;
    int ci   = k & 255;
    const float* wp = W + co * K_TOT + ci * 9 + khkw;
    unsigned int pk = 0;
    #pragma unroll
    for (int j = 0; j < 4; ++j) {
        unsigned int b = (wp[j * 9] >= 0.f) ? 0x01u : 0xFFu;
        pk |= b << (8 * j);
    }
    wq4[i4] = pk;
}

// ---------------- x: f32 NCHW -> i8 NHWC padded [n][h+1][w+1][ci], halo fused
__global__ void __launch_bounds__(256) transpose_pad_kernel(const float* __restrict__ x,
                                                            signed char* __restrict__ xp) {
    __shared__ __align__(4) signed char s[HW * 260];   // stride 260B = 65 dwords (odd)
    const int t = threadIdx.x;
    const int h = blockIdx.x;
    const int n = blockIdx.y;
    const float* xrow = x + ((n * C_IN) * HW + h) * HW;
    const float QI = 127.0f / QCLIP;

    #pragma unroll 4
    for (int i = 0; i < 64; ++i) {
        int idx = i * 256 + t;
        int ci = idx >> 6, w = idx & 63;
        if (w < HW) {
            int q = __float2int_rn(xrow[ci * PIX + w] * QI);
            q = q > 127 ? 127 : (q < -127 ? -127 : q);
            s[w * 260 + ci] = (signed char)q;
        }
    }
    __syncthreads();
    unsigned int* xp32 = (unsigned int*)xp;
    #pragma unroll 4
    for (int i = 0; i < 14; ++i) {
        int idx = i * 256 + t;                        // dword over 56*64
        int w = idx >> 6, cq = idx & 63;
        unsigned int d = *(const unsigned int*)&s[w * 260 + cq * 4];
        xp32[((n * HP + h + 1) * HP + (w + 1)) * 64 + cq] = d;
    }
    // fused halo zeros
    if (t < 64) {
        xp32[((n * HP + h + 1) * HP + 0)  * 64 + t] = 0u;
        xp32[((n * HP + h + 1) * HP + 57) * 64 + t] = 0u;
    }
    if (h == 0) {
        unsigned int* row = xp32 + (unsigned int)(n * HP + 0) * HP * 64;
        for (int i = t; i < HP * 64; i += 256) row[i] = 0u;
    }
    if (h == HW - 1) {
        unsigned int* row = xp32 + (unsigned int)(n * HP + 57) * HP * 64;
        for (int i = t; i < HP * 64; i += 256) row[i] = 0u;
    }
}

// ---------------- i8 GEMM: 3 buffers x (X 16KB + W 16KB) = 96KB.
// Region rows [256][64B]; swizzle: 16B chunk c of 64B row at c^((row>>1)&3).
#define XS(b)   ((b)*32768)
#define WS_(b)  ((b)*32768 + 16384)

__device__ __forceinline__ int xko(int kabs) {       // im2col offset into xpad (i8)
    int khkw = kabs >> 8;                            // 0..8 (uniform)
    int kh = (khkw * 11) >> 5;                       // /3 for 0..8
    int kw = khkw - kh * 3;
    return (kh * HP + kw) * C_IN + (kabs & 255);
}

__global__ void __launch_bounds__(512, 2)
conv_gemm_kernel(const signed char* __restrict__ xpad,
                 const signed char* __restrict__ wq,
                 float* __restrict__ out) {
    __shared__ __align__(16) signed char LDSBUF[98304];   // 96 KiB

    const int t    = threadIdx.x;
    const int lane = t & 63;
    const int wid  = t >> 6;
    const int wpx  = wid >> 2;       // 0..1 : 112-px half
    const int wco  = wid & 3;        // 0..3 : 64-co quarter
    const int l15  = lane & 15;
    const int l4   = lane >> 4;      // 16B k-chunk within 64B row
    const int t16  = t * 16;

    int bid = (int)blockIdx.x;
    bid = (bid & 7) * (NBLK / 8) + (bid >> 3);      // XCD swizzle (448 = 8*56)
    const int m0 = bid * BM;

    // read-side LDS byte offsets (within one 16KB region)
    int xrd[7], wrd[4];
    #pragma unroll
    for (int i = 0; i < 7; ++i) {
        int r = wpx * 112 + i * 16 + l15;
        xrd[i] = r * 64 + ((l4 ^ ((r >> 1) & 3)) << 4);
    }
    #pragma unroll
    for (int j = 0; j < 4; ++j) {
        int r = wco * 64 + j * 16 + l15;
        wrd[j] = r * 64 + ((l4 ^ ((r >> 1) & 3)) << 4);
    }

    // stage-side: half0 -> rows 0..127 (dest t*16), half1 -> rows 128..255 (+8192)
    const int lc16 = ((t & 3) ^ ((t >> 3) & 3)) << 4;    // inverse-swizzled k offset
    int rbA, rbB;
    {
        int rA = t >> 2;
        int rB = 128 + rA; if (rB > BM - 1) rB = BM - 1;   // rows 224..255: dup, never read
        int mA = m0 + rA, mB = m0 + rB;
        int nA = mA / PIX, pA = mA - nA * PIX, hA = pA / HW, wA = pA - hA * HW;
        int nB = mB / PIX, pB = mB - nB * PIX, hB = pB / HW, wB2 = pB - hB * HW;
        rbA = ((nA * HP + hA) * HP + wA) * C_IN + lc16;
        rbB = ((nB * HP + hB) * HP + wB2) * C_IN + lc16;
    }
    int wgA, wgB;
    {
        int rA = t >> 2;
        wgA = rA * K_TOT + lc16;
        wgB = (128 + rA) * K_TOT + lc16;
    }

#define GLD(gp, off) __builtin_amdgcn_global_load_lds( \
        (const __attribute__((address_space(1))) void*)(gp), \
        (__attribute__((address_space(3))) void*)(LDSBUF + (off)), 16, 0, 0)
#define LDXF(i,b)  (*(const i32x4*)(LDSBUF + XS(b) + xrd[i]))
#define LDWF(j,b)  (*(const i32x4*)(LDSBUF + WS_(b) + wrd[j]))

    i32x4 acc[7][4];
    #pragma unroll
    for (int i = 0; i < 7; ++i)
        #pragma unroll
        for (int j = 0; j < 4; ++j)
            acc[i][j] = (i32x4){0, 0, 0, 0};

    i32x4 wf[4];

#define MF2(r0, X0, X1) \
        _Pragma("unroll") \
        for (int j_ = 0; j_ < 4; ++j_) { \
            acc[r0][j_]     = __builtin_amdgcn_mfma_i32_16x16x64_i8(wf[j_], X0, acc[r0][j_], 0, 0, 0); \
            acc[(r0)+1][j_] = __builtin_amdgcn_mfma_i32_16x16x64_i8(wf[j_], X1, acc[(r0)+1][j_], 0, 0, 0); \
        }
#define MF1(r0, X0) \
        _Pragma("unroll") \
        for (int j_ = 0; j_ < 4; ++j_) \
            acc[r0][j_] = __builtin_amdgcn_mfma_i32_16x16x64_i8(wf[j_], X0, acc[r0][j_], 0, 0, 0);

    // phase sync (m201 discipline): reads+stage BEFORE barrier; lgkmcnt(0)
    // after barrier (transfer hides under barrier wait); MFMA cluster clean;
    // closing barrier keeps waves phase-locked. rule 18: sched_barrier after
    // the inline-asm waits.
#define SYNC_IN \
        __builtin_amdgcn_sched_barrier(0); \
        __builtin_amdgcn_s_barrier(); \
        asm volatile("s_waitcnt lgkmcnt(0)" ::: "memory"); \
        __builtin_amdgcn_sched_barrier(0); \
        __builtin_amdgcn_s_setprio(1)
#define SYNC_OUT \
        __builtin_amdgcn_s_setprio(0); \
        __builtin_amdgcn_sched_barrier(0); \
        __builtin_amdgcn_s_barrier(); \
        __builtin_amdgcn_sched_barrier(0)
#define SYNC_OUT_V \
        __builtin_amdgcn_s_setprio(0); \
        asm volatile("s_waitcnt vmcnt(4)" ::: "memory"); \
        __builtin_amdgcn_sched_barrier(0); \
        __builtin_amdgcn_s_barrier(); \
        __builtin_amdgcn_sched_barrier(0)

    // Tile t (buf b=t%3): 4 phases; stages tile t+2 -> buf sb=(t+2)%3, one GLD
    // per phase in order {X h0, X h1, W h0, W h1}. vmcnt(4) at P4 keeps this
    // tile's 4 in-flight GLDs, retiring tile t+1's stages (published by the
    // closing barrier, read at tile t+1 P1). Restage target buf sb held tile
    // t-1, whose ds_reads were lgkm-complete before its last barrier.
#define TILE(b, sb, Ts) { \
        const int koS = xko((Ts) * 64); \
        const int kaS = (Ts) * 64; \
        i32x4 x0, x1; \
        x0 = LDXF(0, b); x1 = LDXF(1, b); \
        wf[0] = LDWF(0, b); wf[1] = LDWF(1, b); wf[2] = LDWF(2, b); wf[3] = LDWF(3, b); \
        GLD(xpad + rbA + koS, XS(sb) + t16); \
        SYNC_IN; MF2(0, x0, x1); SYNC_OUT; \
        x0 = LDXF(2, b); x1 = LDXF(3, b); \
        GLD(xpad + rbB + koS, XS(sb) + 8192 + t16); \
        SYNC_IN; MF2(2, x0, x1); SYNC_OUT; \
        x0 = LDXF(4, b); x1 = LDXF(5, b); \
        GLD(wq + wgA + kaS, WS_(sb) + t16); \
        SYNC_IN; MF2(4, x0, x1); SYNC_OUT; \
        x0 = LDXF(6, b); \
        GLD(wq + wgB + kaS, WS_(sb) + 8192 + t16); \
        SYNC_IN; MF1(6, x0); SYNC_OUT_V; \
    }

    // prologue: stage tile 0 -> buf0, tile 1 -> buf1 (8 GLD, order X0h0 X0h1
    // W0h0 W0h1 X1h0 X1h1 W1h0 W1h1); vmcnt(4) retires tile 0; barrier.
    {
        int ko0 = xko(0), ko1 = xko(64);
        GLD(xpad + rbA + ko0, XS(0) + t16);
        GLD(xpad + rbB + ko0, XS(0) + 8192 + t16);
        GLD(wq + wgA + 0, WS_(0) + t16);
        GLD(wq + wgB + 0, WS_(0) + 8192 + t16);
        GLD(xpad + rbA + ko1, XS(1) + t16);
        GLD(xpad + rbB + ko1, XS(1) + 8192 + t16);
        GLD(wq + wgA + 64, WS_(1) + t16);
        GLD(wq + wgB + 64, WS_(1) + 8192 + t16);
    }
    asm volatile("s_waitcnt vmcnt(4)" ::: "memory");
    __builtin_amdgcn_sched_barrier(0);
    __builtin_amdgcn_s_barrier();
    __builtin_amdgcn_sched_barrier(0);

    #pragma unroll 1
    for (int it = 0; it < 12; ++it) {
        const int T0 = 3 * it;
        int s0 = T0 + 2; if (s0 > NT - 1) s0 = NT - 1;
        int s1 = T0 + 3; if (s1 > NT - 1) s1 = NT - 1;
        int s2 = T0 + 4; if (s2 > NT - 1) s2 = NT - 1;
        TILE(0, 2, s0);
        TILE(1, 0, s1);
        TILE(2, 1, s2);
    }
    asm volatile("s_waitcnt vmcnt(0)" ::: "memory");   // drain stage GLDs

    // epilogue: C row=co (l4*4+r), col=px (l15); dequant by QCLIP/127
    const float QS = QCLIP / 127.0f;
    const int nimg = m0 / PIX;                // exact: 3136 = 14*224
    const int p0   = m0 - nimg * PIX;
    float* ob = out + nimg * (C_OUT * PIX);
    #pragma unroll
    for (int i = 0; i < 7; ++i) {
        int p = p0 + wpx * 112 + i * 16 + l15;
        #pragma unroll
        for (int j = 0; j < 4; ++j) {
            int co = wco * 64 + j * 16 + l4 * 4;
            #pragma unroll
            for (int r = 0; r < 4; ++r)
                ob[(co + r) * PIX + p] = (float)acc[i][j][r] * QS;
        }
    }
#undef TILE
#undef MF2
#undef MF1
#undef SYNC_IN
#undef SYNC_OUT
#undef SYNC_OUT_V
#undef GLD
#undef LDXF
#undef LDWF
}

// ---------------- fallback: naive direct conv
__global__ void __launch_bounds__(256) conv_naive_kernel(const float* __restrict__ x,
                                                         const float* __restrict__ W,
                                                         float* __restrict__ out) {
    int idx = blockIdx.x * 256 + threadIdx.x;
    int w = idx % HW;
    int tmp = idx / HW;
    int h = tmp % HW;
    tmp /= HW;
    int co = tmp & 255;
    int n  = tmp >> 8;
    const float* xn = x + n * (C_IN * PIX);
    const float* wc = W + co * K_TOT;
    float acc = 0.f;
    for (int ci = 0; ci < C_IN; ++ci) {
        const float* xc = xn + ci * PIX;
        const float* wk = wc + ci * 9;
        #pragma unroll
        for (int kh = 0; kh < 3; ++kh) {
            int hh = h + kh - 1;
            if (hh < 0 || hh >= HW) continue;
            #pragma unroll
            for (int kw = 0; kw < 3; ++kw) {
                int ww = w + kw - 1;
                if (ww < 0 || ww >= HW) continue;
                float xv = xc[hh * HW + ww];
                acc += (wk[kh * 3 + kw] >= 0.f) ? xv : -xv;
            }
        }
    }
    out[idx] = acc;
}

extern "C" void kernel_launch(void* const* d_in, const int* in_sizes, int n_in,
                              void* d_out, int out_size, void* d_ws, size_t ws_size,
                              hipStream_t stream) {
    const float* x = (const float*)d_in[0];
    const float* W = (const float*)d_in[1];
    float* out = (float*)d_out;

    if (ws_size < (size_t)WS_NEEDED) {
        int total = N_IMG * C_OUT * PIX;
        conv_naive_kernel<<<(total + 255) / 256, 256, 0, stream>>>(x, W, out);
        return;
    }

    unsigned int* wq4   = (unsigned int*)d_ws;
    signed char*  xpad  = (signed char*)d_ws + WQ_BYTES;

    binW_kernel<<<(WQ_BYTES / 4) / 256, 256, 0, stream>>>(W, wq4);
    transpose_pad_kernel<<<dim3(HW, N_IMG), 256, 0, stream>>>(x, xpad);
    conv_gemm_kernel<<<dim3(NBLK), 512, 0, stream>>>(xpad, (const signed char*)wq4, out);
}